// Round 1
// 1627.542 us; speedup vs baseline: 2.0517x; 2.0517x over previous
//
#include <hip/hip_runtime.h>

// B=8, S=2048, D_MODEL=1024, HEAD_DIM=64, NUM_HEADS=16 (all heads identical).
// out = softmax((X Wq)(X Wk)^T / 8) (X Wv) @ Wo_sum + bo, Wo_sum[d,j] = sum_h Wo[h*64+d, j].
// Round 5: attention rewritten as LDS-tiled flash kernel (64 q-rows/block, 64-key tiles,
// online softmax, 4x4 register blocking). out_s retiled to 8 rows/block for wosum reuse.
// proj_s: 4 independent accumulators + per-block (not per-thread) dtype sniffing.

__device__ __forceinline__ float bf2f(unsigned short u) {
    unsigned int x = ((unsigned int)u) << 16;
    return __builtin_bit_cast(float, x);
}

__device__ __forceinline__ bool detect_bf16(const void* p, int nwords) {
    const unsigned short* w = (const unsigned short*)p;
    int sane = 0;
    for (int i = 0; i < nwords; ++i) {
        unsigned e = (w[i] >> 7) & 0xFF;
        sane += (e == 0 || (e >= 0x60 && e <= 0x9F)) ? 1 : 0;
    }
    return sane * 10 >= nwords * 9;
}

__device__ __forceinline__ float load_in(const void* p, long idx, bool isbf16) {
    return isbf16 ? bf2f(((const unsigned short*)p)[idx]) : ((const float*)p)[idx];
}

// ---------------- Wo_sum[64][1024] (f32) ----------------
__global__ __launch_bounds__(256) void prep_wosum(const void* __restrict__ Wo,
                                                  float* __restrict__ wosum) {
    __shared__ bool fwb;
    if (threadIdx.x == 0) fwb = detect_bf16(Wo, 256);
    __syncthreads();
    bool wb = fwb;
    int id = blockIdx.x * 256 + threadIdx.x;   // 65536
    int d = id >> 10, n = id & 1023;
    float s = 0.f;
#pragma unroll
    for (int h = 0; h < 16; ++h) s += load_in(Wo, (long)(h * 64 + d) * 1024 + n, wb);
    wosum[id] = s;
}

// ---------------- projections: q/k/v[16384][64] f32, row-major ----------------
// grid (4096, 3) x 256. Thread t: row = bx*4 + (t>>6), col = t&63.
// 4 accumulators break the 1024-long serial FMA chain; dtype sniff once per block.
__global__ __launch_bounds__(256) void proj_s(
    const void* __restrict__ X0, const void* __restrict__ X1, const void* __restrict__ X2,
    const void* __restrict__ bq, const void* __restrict__ bk, const void* __restrict__ bv,
    const void* __restrict__ Wq, const void* __restrict__ Wk, const void* __restrict__ Wv,
    float* __restrict__ qo, float* __restrict__ ko, float* __restrict__ vo) {
    int p = blockIdx.y;
    const void* X    = (p == 0) ? X0 : (p == 1) ? X1 : X2;
    const void* W    = (p == 0) ? Wq : (p == 1) ? Wk : Wv;
    const void* bias = (p == 0) ? bq : (p == 1) ? bk : bv;
    float* out       = (p == 0) ? qo : (p == 1) ? ko : vo;
    __shared__ bool fxb, fwb, fbb;
    if (threadIdx.x == 0) {
        fxb = detect_bf16(X, 256);
        fwb = detect_bf16(W, 256);
        fbb = detect_bf16(bias, 64);
    }
    __syncthreads();
    bool xb = fxb, wb = fwb, bb = fbb;
    int t = threadIdx.x;
    int rl = t >> 6, col = t & 63;
    long row = (long)blockIdx.x * 4 + rl;
    long xbase = row * 1024;
    float a0 = 0.f, a1 = 0.f, a2 = 0.f, a3 = 0.f;
    for (int k2 = 0; k2 < 1024; k2 += 4) {
        float x0 = load_in(X, xbase + k2 + 0, xb);
        float x1 = load_in(X, xbase + k2 + 1, xb);
        float x2 = load_in(X, xbase + k2 + 2, xb);
        float x3 = load_in(X, xbase + k2 + 3, xb);
        a0 += x0 * load_in(W, (long)(k2 + 0) * 64 + col, wb);
        a1 += x1 * load_in(W, (long)(k2 + 1) * 64 + col, wb);
        a2 += x2 * load_in(W, (long)(k2 + 2) * 64 + col, wb);
        a3 += x3 * load_in(W, (long)(k2 + 3) * 64 + col, wb);
    }
    out[row * 64 + col] = load_in(bias, col, bb) + ((a0 + a1) + (a2 + a3));
}

// ---------------- attention: tiled flash kernel ----------------
// grid (32, 8) x 256: block = 64 q-rows of one batch; loop over 32 tiles of 64 keys.
// Thread map: qg4=(tid>>4)*4 (4 q-rows), g16=tid&15 -> 4 keys (S) / 4 dims (O).
// LDS: Qt[d][q] (pre-scaled by 1/8), Kt[d][k], Pt[k][q]; strides 68 floats (no conflicts).
// Row statistics (max, sum) reduced across the 16 lanes of a q-group via shfl_xor 1/2/4/8.
__global__ __launch_bounds__(256) void attn_t(const float* __restrict__ q,
                                              const float* __restrict__ k,
                                              const float* __restrict__ v,
                                              float* __restrict__ ctx) {
    const int b = blockIdx.y;
    const long kvbase = (long)b * 2048;
    const long qbase  = kvbase + (long)blockIdx.x * 64;

    __shared__ __align__(16) float Qt[64 * 68];
    __shared__ __align__(16) float Kt[64 * 68];
    __shared__ __align__(16) float Pt[64 * 68];

    const int tid = threadIdx.x;
    const int qg4 = (tid >> 4) * 4;   // this thread's 4 q-rows
    const int g16 = tid & 15;
    const int kg4 = g16 * 4;          // S: 4 keys
    const int dg4 = g16 * 4;          // O: 4 dims
    const int sr0 = (tid >> 4) * 4;   // staging: 4 source rows
    const int sd4 = (tid & 15) * 4;   // staging: 4 dims

    // stage Q transposed, pre-scaled by 1/sqrt(64)
    {
        const float* qp = &q[(qbase + sr0) * 64 + sd4];
        float4 a0 = *(const float4*)(qp);
        float4 a1 = *(const float4*)(qp + 64);
        float4 a2 = *(const float4*)(qp + 128);
        float4 a3 = *(const float4*)(qp + 192);
        const float sc = 0.125f;
        *(float4*)&Qt[(sd4 + 0) * 68 + sr0] = make_float4(a0.x * sc, a1.x * sc, a2.x * sc, a3.x * sc);
        *(float4*)&Qt[(sd4 + 1) * 68 + sr0] = make_float4(a0.y * sc, a1.y * sc, a2.y * sc, a3.y * sc);
        *(float4*)&Qt[(sd4 + 2) * 68 + sr0] = make_float4(a0.z * sc, a1.z * sc, a2.z * sc, a3.z * sc);
        *(float4*)&Qt[(sd4 + 3) * 68 + sr0] = make_float4(a0.w * sc, a1.w * sc, a2.w * sc, a3.w * sc);
    }

    float o[4][4] = {};
    float m[4] = {-INFINITY, -INFINITY, -INFINITY, -INFINITY};
    float l[4] = {};

    for (int t0 = 0; t0 < 2048; t0 += 64) {
        // stage K tile transposed (coalesced reads, conflict-free b128 writes)
        {
            const float* kp = &k[(kvbase + t0 + sr0) * 64 + sd4];
            float4 a0 = *(const float4*)(kp);
            float4 a1 = *(const float4*)(kp + 64);
            float4 a2 = *(const float4*)(kp + 128);
            float4 a3 = *(const float4*)(kp + 192);
            *(float4*)&Kt[(sd4 + 0) * 68 + sr0] = make_float4(a0.x, a1.x, a2.x, a3.x);
            *(float4*)&Kt[(sd4 + 1) * 68 + sr0] = make_float4(a0.y, a1.y, a2.y, a3.y);
            *(float4*)&Kt[(sd4 + 2) * 68 + sr0] = make_float4(a0.z, a1.z, a2.z, a3.z);
            *(float4*)&Kt[(sd4 + 3) * 68 + sr0] = make_float4(a0.w, a1.w, a2.w, a3.w);
        }
        __syncthreads();   // A: Kt ready; everyone done with previous PV

        // QK^T: s[4 q][4 k], 16 independent FMA chains
        float s[4][4] = {};
#pragma unroll 4
        for (int d = 0; d < 64; ++d) {
            float4 qv = *(const float4*)&Qt[d * 68 + qg4];
            float4 kv = *(const float4*)&Kt[d * 68 + kg4];
            float qa[4] = {qv.x, qv.y, qv.z, qv.w};
            float ka[4] = {kv.x, kv.y, kv.z, kv.w};
#pragma unroll
            for (int qi = 0; qi < 4; ++qi)
#pragma unroll
                for (int kj = 0; kj < 4; ++kj) s[qi][kj] += qa[qi] * ka[kj];
        }

        // online softmax update
#pragma unroll
        for (int qi = 0; qi < 4; ++qi) {
            float pm = fmaxf(fmaxf(s[qi][0], s[qi][1]), fmaxf(s[qi][2], s[qi][3]));
            pm = fmaxf(pm, __shfl_xor(pm, 1));
            pm = fmaxf(pm, __shfl_xor(pm, 2));
            pm = fmaxf(pm, __shfl_xor(pm, 4));
            pm = fmaxf(pm, __shfl_xor(pm, 8));
            float mn = fmaxf(m[qi], pm);
            float f = __expf(m[qi] - mn);
            m[qi] = mn;
            float ts = 0.f;
#pragma unroll
            for (int kj = 0; kj < 4; ++kj) {
                float pv = __expf(s[qi][kj] - mn);
                s[qi][kj] = pv;
                ts += pv;
            }
            ts += __shfl_xor(ts, 1);
            ts += __shfl_xor(ts, 2);
            ts += __shfl_xor(ts, 4);
            ts += __shfl_xor(ts, 8);
            l[qi] = l[qi] * f + ts;
#pragma unroll
            for (int di = 0; di < 4; ++di) o[qi][di] *= f;
        }

        // write P^T to LDS for the q<->d remap
#pragma unroll
        for (int kj = 0; kj < 4; ++kj)
            *(float4*)&Pt[(kg4 + kj) * 68 + qg4] = make_float4(s[0][kj], s[1][kj], s[2][kj], s[3][kj]);
        __syncthreads();   // B: Pt ready (also: all Kt reads of this tile done)

        // PV: o[4 q][4 d] += P[q][k] * V[k][d]; V read straight from L2 (coalesced 256B/wave)
        const float* vb = &v[(kvbase + t0) * 64 + dg4];
#pragma unroll 4
        for (int kk = 0; kk < 64; ++kk) {
            float4 p4 = *(const float4*)&Pt[kk * 68 + qg4];
            float4 v4 = *(const float4*)&vb[kk * 64];
            float pa[4] = {p4.x, p4.y, p4.z, p4.w};
            float va[4] = {v4.x, v4.y, v4.z, v4.w};
#pragma unroll
            for (int qi = 0; qi < 4; ++qi)
#pragma unroll
                for (int di = 0; di < 4; ++di) o[qi][di] += pa[qi] * va[di];
        }
    }

#pragma unroll
    for (int qi = 0; qi < 4; ++qi) {
        float inv = 1.f / l[qi];
        *(float4*)&ctx[(qbase + qg4 + qi) * 64 + dg4] =
            make_float4(o[qi][0] * inv, o[qi][1] * inv, o[qi][2] * inv, o[qi][3] * inv);
    }
}

// ---------------- output: out[16384][1024] = ctx @ Wo_sum + bo ----------------
// grid 2048 x 256: block = 8 ctx rows; wosum read once per block (float4, coalesced),
// reused across 8 rows -> wosum L2 traffic 4 GB -> 0.5 GB.
__global__ __launch_bounds__(256) void out_t(const float* __restrict__ ctx,
                                             const float* __restrict__ wosum,
                                             const void* __restrict__ bo,
                                             float* __restrict__ out) {
    __shared__ __align__(16) float cr[8 * 64];
    __shared__ bool fbb;
    int t = threadIdx.x;
    long row0 = (long)blockIdx.x * 8;
    if (t == 0) fbb = detect_bf16(bo, 256);
    if (t < 128) {
        int r = t >> 4, d4 = (t & 15) * 4;
        *(float4*)&cr[r * 64 + d4] = *(const float4*)&ctx[(row0 + r) * 64 + d4];
    }
    __syncthreads();
    bool bob = fbb;
    int c = t * 4;
    float a[8][4];
    {
        float b0 = load_in(bo, c + 0, bob), b1 = load_in(bo, c + 1, bob);
        float b2 = load_in(bo, c + 2, bob), b3 = load_in(bo, c + 3, bob);
#pragma unroll
        for (int r = 0; r < 8; ++r) { a[r][0] = b0; a[r][1] = b1; a[r][2] = b2; a[r][3] = b3; }
    }
#pragma unroll 4
    for (int d = 0; d < 64; ++d) {
        float4 w4 = *(const float4*)&wosum[d * 1024 + c];
#pragma unroll
        for (int r = 0; r < 8; ++r) {
            float cv = cr[r * 64 + d];
            a[r][0] += cv * w4.x;
            a[r][1] += cv * w4.y;
            a[r][2] += cv * w4.z;
            a[r][3] += cv * w4.w;
        }
    }
#pragma unroll
    for (int r = 0; r < 8; ++r)
        *(float4*)&out[(row0 + r) * 1024 + c] = make_float4(a[r][0], a[r][1], a[r][2], a[r][3]);
}

extern "C" void kernel_launch(void* const* d_in, const int* in_sizes, int n_in,
                              void* d_out, int out_size, void* d_ws, size_t ws_size,
                              hipStream_t stream) {
    // Defensive routing by size class (identity if inputs are in dict order):
    // 16777216 -> query,key,value ; 65536 -> Wq,Wk,Wv ; 64 -> bq,bk,bv ;
    // 1048576 -> Wo ; 1024 -> bo. in_sizes are element counts (dtype-independent).
    const void* big[3] = {0, 0, 0};  int nbig = 0;
    const void* w64k[3] = {0, 0, 0}; int nw = 0;
    const void* b64[3] = {0, 0, 0};  int nb = 0;
    const void* Wo = 0; const void* bo = 0;
    for (int i = 0; i < n_in; ++i) {
        int s = in_sizes[i];
        if (s == 16777216 && nbig < 3)     big[nbig++] = d_in[i];
        else if (s == 65536 && nw < 3)     w64k[nw++] = d_in[i];
        else if (s == 64 && nb < 3)        b64[nb++] = d_in[i];
        else if (s == 1048576)             Wo = d_in[i];
        else if (s == 1024)                bo = d_in[i];
    }
    const void* query = big[0]  ? big[0]  : d_in[0];
    const void* key   = big[1]  ? big[1]  : d_in[1];
    const void* value = big[2]  ? big[2]  : d_in[2];
    const void* Wq    = w64k[0] ? w64k[0] : d_in[3];
    const void* Wk    = w64k[1] ? w64k[1] : d_in[5];
    const void* Wv    = w64k[2] ? w64k[2] : d_in[7];
    const void* bq    = b64[0]  ? b64[0]  : d_in[4];
    const void* bk    = b64[1]  ? b64[1]  : d_in[6];
    const void* bv    = b64[2]  ? b64[2]  : d_in[8];
    if (!Wo) Wo = d_in[9];
    if (!bo) bo = d_in[10];
    float* out = (float*)d_out;

    char* ws = (char*)d_ws;
    float* wosum = (float*)(ws);                      // 256 KB
    float* q     = (float*)(ws + 1048576);            // 4 MB
    float* k     = (float*)(ws + 1048576 + 4194304);  // 4 MB
    float* v     = (float*)(ws + 1048576 + 2*4194304);// 4 MB
    float* ctx   = (float*)(ws + 1048576 + 3*4194304);// 4 MB

    hipLaunchKernelGGL(prep_wosum, dim3(256),       dim3(256), 0, stream, Wo, wosum);
    hipLaunchKernelGGL(proj_s,     dim3(4096, 3),   dim3(256), 0, stream,
                       query, key, value, bq, bk, bv, Wq, Wk, Wv, q, k, v);
    hipLaunchKernelGGL(attn_t,     dim3(32, 8),     dim3(256), 0, stream, q, k, v, ctx);
    hipLaunchKernelGGL(out_t,      dim3(2048),      dim3(256), 0, stream, ctx, wosum, bo, out);
}

// Round 2
// 621.165 us; speedup vs baseline: 5.3758x; 2.6201x over previous
//
#include <hip/hip_runtime.h>

// B=8, S=2048, D_MODEL=1024, HEAD_DIM=64, NUM_HEADS=16 (all heads identical).
// out = softmax((X Wq)(X Wk)^T / 8) (X Wv) @ Wo_sum + bo, Wo_sum[d,j] = sum_h Wo[h*64+d, j].
// Round 6: projections rewritten as LDS-tiled register-blocked GEMM (64x64 tile, K-step 64,
// 4x4 register tile per thread, vectorized bf16/f32 staging). proj_s was 73% of runtime at
// VALUBusy=22% / VGPR=16: 2-byte scalar loads, no tiling -> latency-bound. attn_t/out_t
// unchanged from round 5 (attn_t dropped out of top-5; counters next round).

typedef __attribute__((ext_vector_type(8))) unsigned short ushort8v;

__device__ __forceinline__ float bf2f(unsigned short u) {
    unsigned int x = ((unsigned int)u) << 16;
    return __builtin_bit_cast(float, x);
}

__device__ __forceinline__ bool detect_bf16(const void* p, int nwords) {
    const unsigned short* w = (const unsigned short*)p;
    int sane = 0;
    for (int i = 0; i < nwords; ++i) {
        unsigned e = (w[i] >> 7) & 0xFF;
        sane += (e == 0 || (e >= 0x60 && e <= 0x9F)) ? 1 : 0;
    }
    return sane * 10 >= nwords * 9;
}

__device__ __forceinline__ float load_in(const void* p, long idx, bool isbf16) {
    return isbf16 ? bf2f(((const unsigned short*)p)[idx]) : ((const float*)p)[idx];
}

// ---------------- Wo_sum[64][1024] (f32) ----------------
__global__ __launch_bounds__(256) void prep_wosum(const void* __restrict__ Wo,
                                                  float* __restrict__ wosum) {
    __shared__ bool fwb;
    if (threadIdx.x == 0) fwb = detect_bf16(Wo, 256);
    __syncthreads();
    bool wb = fwb;
    int id = blockIdx.x * 256 + threadIdx.x;   // 65536
    int d = id >> 10, n = id & 1023;
    float s = 0.f;
#pragma unroll
    for (int h = 0; h < 16; ++h) s += load_in(Wo, (long)(h * 64 + d) * 1024 + n, wb);
    wosum[id] = s;
}

// ---------------- projections: q/k/v[16384][64] f32 = X[16384][1024] @ W[1024][64] + b ----
// grid (256, 3) x 256. Block = 64 rows x 64 cols output tile; K-loop in steps of 64.
// LDS: Xt[k][row] (transposed, stride 68), Ws[k][col] (stride 68). Thread: 4x4 register
// tile, row4=(t>>4)*4, col4=(t&15)*4 -> 16 independent FMA chains, b128 LDS reads
// (4-address broadcast on Xt, 16-address sweep on Ws; both at the wave64-b128 floor).
__global__ __launch_bounds__(256) void proj_t(
    const void* __restrict__ X0, const void* __restrict__ X1, const void* __restrict__ X2,
    const void* __restrict__ bq, const void* __restrict__ bk, const void* __restrict__ bv,
    const void* __restrict__ Wq, const void* __restrict__ Wk, const void* __restrict__ Wv,
    float* __restrict__ qo, float* __restrict__ ko, float* __restrict__ vo) {
    int p = blockIdx.y;
    const void* X    = (p == 0) ? X0 : (p == 1) ? X1 : X2;
    const void* W    = (p == 0) ? Wq : (p == 1) ? Wk : Wv;
    const void* bias = (p == 0) ? bq : (p == 1) ? bk : bv;
    float* out       = (p == 0) ? qo : (p == 1) ? ko : vo;

    __shared__ bool fxb, fwb, fbb;
    __shared__ __align__(16) float Xt[64 * 68];
    __shared__ __align__(16) float Ws[64 * 68];
    if (threadIdx.x == 0) {
        fxb = detect_bf16(X, 256);
        fwb = detect_bf16(W, 256);
        fbb = detect_bf16(bias, 64);
    }
    __syncthreads();
    const bool xb = fxb, wb = fwb, bb = fbb;

    const int t = threadIdx.x;
    const long row0 = (long)blockIdx.x * 64;
    const int row4 = (t >> 4) * 4;   // compute: 4 output rows
    const int col4 = (t & 15) * 4;   // compute: 4 output cols
    const int sr0 = (t >> 4) * 4;    // X stage: 4 source rows
    const int sk4 = (t & 15) * 4;    // X stage: 4 k within step
    const int wk  = t >> 2;          // W stage: k row 0..63
    const int wc0 = (t & 3) * 16;    // W stage: 16 cols

    float acc[4][4] = {};

    for (int k0 = 0; k0 < 1024; k0 += 64) {
        // ---- stage X^T tile: Xt[kk][row], kk = k within step ----
        if (xb) {
            const unsigned short* xp =
                (const unsigned short*)X + (row0 + sr0) * 1024 + k0 + sk4;
            ushort4 u0 = *(const ushort4*)(xp);
            ushort4 u1 = *(const ushort4*)(xp + 1024);
            ushort4 u2 = *(const ushort4*)(xp + 2048);
            ushort4 u3 = *(const ushort4*)(xp + 3072);
            *(float4*)&Xt[(sk4 + 0) * 68 + sr0] =
                make_float4(bf2f(u0.x), bf2f(u1.x), bf2f(u2.x), bf2f(u3.x));
            *(float4*)&Xt[(sk4 + 1) * 68 + sr0] =
                make_float4(bf2f(u0.y), bf2f(u1.y), bf2f(u2.y), bf2f(u3.y));
            *(float4*)&Xt[(sk4 + 2) * 68 + sr0] =
                make_float4(bf2f(u0.z), bf2f(u1.z), bf2f(u2.z), bf2f(u3.z));
            *(float4*)&Xt[(sk4 + 3) * 68 + sr0] =
                make_float4(bf2f(u0.w), bf2f(u1.w), bf2f(u2.w), bf2f(u3.w));
        } else {
            const float* xp = (const float*)X + (row0 + sr0) * 1024 + k0 + sk4;
            float4 a0 = *(const float4*)(xp);
            float4 a1 = *(const float4*)(xp + 1024);
            float4 a2 = *(const float4*)(xp + 2048);
            float4 a3 = *(const float4*)(xp + 3072);
            *(float4*)&Xt[(sk4 + 0) * 68 + sr0] = make_float4(a0.x, a1.x, a2.x, a3.x);
            *(float4*)&Xt[(sk4 + 1) * 68 + sr0] = make_float4(a0.y, a1.y, a2.y, a3.y);
            *(float4*)&Xt[(sk4 + 2) * 68 + sr0] = make_float4(a0.z, a1.z, a2.z, a3.z);
            *(float4*)&Xt[(sk4 + 3) * 68 + sr0] = make_float4(a0.w, a1.w, a2.w, a3.w);
        }
        // ---- stage W tile: Ws[kk][col], row-major copy ----
        if (wb) {
            const unsigned short* wp =
                (const unsigned short*)W + (long)(k0 + wk) * 64 + wc0;
            ushort8v u0 = *(const ushort8v*)(wp);
            ushort8v u1 = *(const ushort8v*)(wp + 8);
            float* wd = &Ws[wk * 68 + wc0];
            *(float4*)(wd + 0)  = make_float4(bf2f(u0[0]), bf2f(u0[1]), bf2f(u0[2]), bf2f(u0[3]));
            *(float4*)(wd + 4)  = make_float4(bf2f(u0[4]), bf2f(u0[5]), bf2f(u0[6]), bf2f(u0[7]));
            *(float4*)(wd + 8)  = make_float4(bf2f(u1[0]), bf2f(u1[1]), bf2f(u1[2]), bf2f(u1[3]));
            *(float4*)(wd + 12) = make_float4(bf2f(u1[4]), bf2f(u1[5]), bf2f(u1[6]), bf2f(u1[7]));
        } else {
            const float* wp = (const float*)W + (long)(k0 + wk) * 64 + wc0;
            float* wd = &Ws[wk * 68 + wc0];
            *(float4*)(wd + 0)  = *(const float4*)(wp + 0);
            *(float4*)(wd + 4)  = *(const float4*)(wp + 4);
            *(float4*)(wd + 8)  = *(const float4*)(wp + 8);
            *(float4*)(wd + 12) = *(const float4*)(wp + 12);
        }
        __syncthreads();

#pragma unroll 4
        for (int kk = 0; kk < 64; ++kk) {
            float4 xv = *(const float4*)&Xt[kk * 68 + row4];
            float4 wv = *(const float4*)&Ws[kk * 68 + col4];
            float xa[4] = {xv.x, xv.y, xv.z, xv.w};
            float wa[4] = {wv.x, wv.y, wv.z, wv.w};
#pragma unroll
            for (int i = 0; i < 4; ++i)
#pragma unroll
                for (int j = 0; j < 4; ++j) acc[i][j] += xa[i] * wa[j];
        }
        __syncthreads();
    }

    float b0 = load_in(bias, col4 + 0, bb);
    float b1 = load_in(bias, col4 + 1, bb);
    float b2 = load_in(bias, col4 + 2, bb);
    float b3 = load_in(bias, col4 + 3, bb);
#pragma unroll
    for (int i = 0; i < 4; ++i)
        *(float4*)&out[(row0 + row4 + i) * 64 + col4] =
            make_float4(acc[i][0] + b0, acc[i][1] + b1, acc[i][2] + b2, acc[i][3] + b3);
}

// ---------------- attention: tiled flash kernel (unchanged from round 5) ----------------
__global__ __launch_bounds__(256) void attn_t(const float* __restrict__ q,
                                              const float* __restrict__ k,
                                              const float* __restrict__ v,
                                              float* __restrict__ ctx) {
    const int b = blockIdx.y;
    const long kvbase = (long)b * 2048;
    const long qbase  = kvbase + (long)blockIdx.x * 64;

    __shared__ __align__(16) float Qt[64 * 68];
    __shared__ __align__(16) float Kt[64 * 68];
    __shared__ __align__(16) float Pt[64 * 68];

    const int tid = threadIdx.x;
    const int qg4 = (tid >> 4) * 4;
    const int g16 = tid & 15;
    const int kg4 = g16 * 4;
    const int dg4 = g16 * 4;
    const int sr0 = (tid >> 4) * 4;
    const int sd4 = (tid & 15) * 4;

    {
        const float* qp = &q[(qbase + sr0) * 64 + sd4];
        float4 a0 = *(const float4*)(qp);
        float4 a1 = *(const float4*)(qp + 64);
        float4 a2 = *(const float4*)(qp + 128);
        float4 a3 = *(const float4*)(qp + 192);
        const float sc = 0.125f;
        *(float4*)&Qt[(sd4 + 0) * 68 + sr0] = make_float4(a0.x * sc, a1.x * sc, a2.x * sc, a3.x * sc);
        *(float4*)&Qt[(sd4 + 1) * 68 + sr0] = make_float4(a0.y * sc, a1.y * sc, a2.y * sc, a3.y * sc);
        *(float4*)&Qt[(sd4 + 2) * 68 + sr0] = make_float4(a0.z * sc, a1.z * sc, a2.z * sc, a3.z * sc);
        *(float4*)&Qt[(sd4 + 3) * 68 + sr0] = make_float4(a0.w * sc, a1.w * sc, a2.w * sc, a3.w * sc);
    }

    float o[4][4] = {};
    float m[4] = {-INFINITY, -INFINITY, -INFINITY, -INFINITY};
    float l[4] = {};

    for (int t0 = 0; t0 < 2048; t0 += 64) {
        {
            const float* kp = &k[(kvbase + t0 + sr0) * 64 + sd4];
            float4 a0 = *(const float4*)(kp);
            float4 a1 = *(const float4*)(kp + 64);
            float4 a2 = *(const float4*)(kp + 128);
            float4 a3 = *(const float4*)(kp + 192);
            *(float4*)&Kt[(sd4 + 0) * 68 + sr0] = make_float4(a0.x, a1.x, a2.x, a3.x);
            *(float4*)&Kt[(sd4 + 1) * 68 + sr0] = make_float4(a0.y, a1.y, a2.y, a3.y);
            *(float4*)&Kt[(sd4 + 2) * 68 + sr0] = make_float4(a0.z, a1.z, a2.z, a3.z);
            *(float4*)&Kt[(sd4 + 3) * 68 + sr0] = make_float4(a0.w, a1.w, a2.w, a3.w);
        }
        __syncthreads();

        float s[4][4] = {};
#pragma unroll 4
        for (int d = 0; d < 64; ++d) {
            float4 qv = *(const float4*)&Qt[d * 68 + qg4];
            float4 kv = *(const float4*)&Kt[d * 68 + kg4];
            float qa[4] = {qv.x, qv.y, qv.z, qv.w};
            float ka[4] = {kv.x, kv.y, kv.z, kv.w};
#pragma unroll
            for (int qi = 0; qi < 4; ++qi)
#pragma unroll
                for (int kj = 0; kj < 4; ++kj) s[qi][kj] += qa[qi] * ka[kj];
        }

#pragma unroll
        for (int qi = 0; qi < 4; ++qi) {
            float pm = fmaxf(fmaxf(s[qi][0], s[qi][1]), fmaxf(s[qi][2], s[qi][3]));
            pm = fmaxf(pm, __shfl_xor(pm, 1));
            pm = fmaxf(pm, __shfl_xor(pm, 2));
            pm = fmaxf(pm, __shfl_xor(pm, 4));
            pm = fmaxf(pm, __shfl_xor(pm, 8));
            float mn = fmaxf(m[qi], pm);
            float f = __expf(m[qi] - mn);
            m[qi] = mn;
            float ts = 0.f;
#pragma unroll
            for (int kj = 0; kj < 4; ++kj) {
                float pv = __expf(s[qi][kj] - mn);
                s[qi][kj] = pv;
                ts += pv;
            }
            ts += __shfl_xor(ts, 1);
            ts += __shfl_xor(ts, 2);
            ts += __shfl_xor(ts, 4);
            ts += __shfl_xor(ts, 8);
            l[qi] = l[qi] * f + ts;
#pragma unroll
            for (int di = 0; di < 4; ++di) o[qi][di] *= f;
        }

#pragma unroll
        for (int kj = 0; kj < 4; ++kj)
            *(float4*)&Pt[(kg4 + kj) * 68 + qg4] = make_float4(s[0][kj], s[1][kj], s[2][kj], s[3][kj]);
        __syncthreads();

        const float* vb = &v[(kvbase + t0) * 64 + dg4];
#pragma unroll 4
        for (int kk = 0; kk < 64; ++kk) {
            float4 p4 = *(const float4*)&Pt[kk * 68 + qg4];
            float4 v4 = *(const float4*)&vb[kk * 64];
            float pa[4] = {p4.x, p4.y, p4.z, p4.w};
            float va[4] = {v4.x, v4.y, v4.z, v4.w};
#pragma unroll
            for (int qi = 0; qi < 4; ++qi)
#pragma unroll
                for (int di = 0; di < 4; ++di) o[qi][di] += pa[qi] * va[di];
        }
    }

#pragma unroll
    for (int qi = 0; qi < 4; ++qi) {
        float inv = 1.f / l[qi];
        *(float4*)&ctx[(qbase + qg4 + qi) * 64 + dg4] =
            make_float4(o[qi][0] * inv, o[qi][1] * inv, o[qi][2] * inv, o[qi][3] * inv);
    }
}

// ---------------- output: out[16384][1024] = ctx @ Wo_sum + bo (unchanged) ----------------
__global__ __launch_bounds__(256) void out_t(const float* __restrict__ ctx,
                                             const float* __restrict__ wosum,
                                             const void* __restrict__ bo,
                                             float* __restrict__ out) {
    __shared__ __align__(16) float cr[8 * 64];
    __shared__ bool fbb;
    int t = threadIdx.x;
    long row0 = (long)blockIdx.x * 8;
    if (t == 0) fbb = detect_bf16(bo, 256);
    if (t < 128) {
        int r = t >> 4, d4 = (t & 15) * 4;
        *(float4*)&cr[r * 64 + d4] = *(const float4*)&ctx[(row0 + r) * 64 + d4];
    }
    __syncthreads();
    bool bob = fbb;
    int c = t * 4;
    float a[8][4];
    {
        float b0 = load_in(bo, c + 0, bob), b1 = load_in(bo, c + 1, bob);
        float b2 = load_in(bo, c + 2, bob), b3 = load_in(bo, c + 3, bob);
#pragma unroll
        for (int r = 0; r < 8; ++r) { a[r][0] = b0; a[r][1] = b1; a[r][2] = b2; a[r][3] = b3; }
    }
#pragma unroll 4
    for (int d = 0; d < 64; ++d) {
        float4 w4 = *(const float4*)&wosum[d * 1024 + c];
#pragma unroll
        for (int r = 0; r < 8; ++r) {
            float cv = cr[r * 64 + d];
            a[r][0] += cv * w4.x;
            a[r][1] += cv * w4.y;
            a[r][2] += cv * w4.z;
            a[r][3] += cv * w4.w;
        }
    }
#pragma unroll
    for (int r = 0; r < 8; ++r)
        *(float4*)&out[(row0 + r) * 1024 + c] = make_float4(a[r][0], a[r][1], a[r][2], a[r][3]);
}

extern "C" void kernel_launch(void* const* d_in, const int* in_sizes, int n_in,
                              void* d_out, int out_size, void* d_ws, size_t ws_size,
                              hipStream_t stream) {
    // Defensive routing by size class (identity if inputs are in dict order):
    // 16777216 -> query,key,value ; 65536 -> Wq,Wk,Wv ; 64 -> bq,bk,bv ;
    // 1048576 -> Wo ; 1024 -> bo. in_sizes are element counts (dtype-independent).
    const void* big[3] = {0, 0, 0};  int nbig = 0;
    const void* w64k[3] = {0, 0, 0}; int nw = 0;
    const void* b64[3] = {0, 0, 0};  int nb = 0;
    const void* Wo = 0; const void* bo = 0;
    for (int i = 0; i < n_in; ++i) {
        int s = in_sizes[i];
        if (s == 16777216 && nbig < 3)     big[nbig++] = d_in[i];
        else if (s == 65536 && nw < 3)     w64k[nw++] = d_in[i];
        else if (s == 64 && nb < 3)        b64[nb++] = d_in[i];
        else if (s == 1048576)             Wo = d_in[i];
        else if (s == 1024)                bo = d_in[i];
    }
    const void* query = big[0]  ? big[0]  : d_in[0];
    const void* key   = big[1]  ? big[1]  : d_in[1];
    const void* value = big[2]  ? big[2]  : d_in[2];
    const void* Wq    = w64k[0] ? w64k[0] : d_in[3];
    const void* Wk    = w64k[1] ? w64k[1] : d_in[5];
    const void* Wv    = w64k[2] ? w64k[2] : d_in[7];
    const void* bq    = b64[0]  ? b64[0]  : d_in[4];
    const void* bk    = b64[1]  ? b64[1]  : d_in[6];
    const void* bv    = b64[2]  ? b64[2]  : d_in[8];
    if (!Wo) Wo = d_in[9];
    if (!bo) bo = d_in[10];
    float* out = (float*)d_out;

    char* ws = (char*)d_ws;
    float* wosum = (float*)(ws);                      // 256 KB
    float* q     = (float*)(ws + 1048576);            // 4 MB
    float* k     = (float*)(ws + 1048576 + 4194304);  // 4 MB
    float* v     = (float*)(ws + 1048576 + 2*4194304);// 4 MB
    float* ctx   = (float*)(ws + 1048576 + 3*4194304);// 4 MB

    hipLaunchKernelGGL(prep_wosum, dim3(256),       dim3(256), 0, stream, Wo, wosum);
    hipLaunchKernelGGL(proj_t,     dim3(256, 3),    dim3(256), 0, stream,
                       query, key, value, bq, bk, bv, Wq, Wk, Wv, q, k, v);
    hipLaunchKernelGGL(attn_t,     dim3(32, 8),     dim3(256), 0, stream, q, k, v, ctx);
    hipLaunchKernelGGL(out_t,      dim3(2048),      dim3(256), 0, stream, ctx, wosum, bo, out);
}

// Round 3
// 544.199 us; speedup vs baseline: 6.1361x; 1.1414x over previous
//
#include <hip/hip_runtime.h>

// B=8, S=2048, D_MODEL=1024, HEAD_DIM=64, NUM_HEADS=16 (all heads identical).
// out = softmax((X Wq)(X Wk)^T / 8) (X Wv) @ Wo_sum + bo, Wo_sum[d,j] = sum_h Wo[h*64+d, j].
// Round 7: attn occupancy fix. Round-6 attn_t ran at 1 block/CU (grid 256 = #CUs), 4 waves/CU,
// OccupancyPercent 11.5, VALUBusy 27%. Split 4x: 32-row q-tiles x 2-way key split + merge
// kernel (flash partial softmax), LDS 52->35 KB -> 4 blocks/CU = 16 waves/CU. K-tile register
// prefetch hides global latency under compute. proj_t gets the same double-buffer prefetch
// (round-6 version exposed ~900cyc HBM latency at each of 16 barrier-separated K-steps).

typedef __attribute__((ext_vector_type(8))) unsigned short ushort8v;

__device__ __forceinline__ float bf2f(unsigned short u) {
    unsigned int x = ((unsigned int)u) << 16;
    return __builtin_bit_cast(float, x);
}

__device__ __forceinline__ bool detect_bf16(const void* p, int nwords) {
    const unsigned short* w = (const unsigned short*)p;
    int sane = 0;
    for (int i = 0; i < nwords; ++i) {
        unsigned e = (w[i] >> 7) & 0xFF;
        sane += (e == 0 || (e >= 0x60 && e <= 0x9F)) ? 1 : 0;
    }
    return sane * 10 >= nwords * 9;
}

__device__ __forceinline__ float load_in(const void* p, long idx, bool isbf16) {
    return isbf16 ? bf2f(((const unsigned short*)p)[idx]) : ((const float*)p)[idx];
}

// ---------------- Wo_sum[64][1024] (f32) ----------------
__global__ __launch_bounds__(256) void prep_wosum(const void* __restrict__ Wo,
                                                  float* __restrict__ wosum) {
    __shared__ bool fwb;
    if (threadIdx.x == 0) fwb = detect_bf16(Wo, 256);
    __syncthreads();
    bool wb = fwb;
    int id = blockIdx.x * 256 + threadIdx.x;   // 65536
    int d = id >> 10, n = id & 1023;
    float s = 0.f;
#pragma unroll
    for (int h = 0; h < 16; ++h) s += load_in(Wo, (long)(h * 64 + d) * 1024 + n, wb);
    wosum[id] = s;
}

// ---------------- projections: q/k/v[16384][64] f32 = X[16384][1024] @ W[1024][64] + b ----
// grid (256, 3) x 256. 64x64 output tile, K-step 64, 4x4 register tile. Double-buffered:
// next X/W tiles are loaded to registers before the inner product, written to LDS after
// the barrier -> HBM latency hides under the 64-step FMA loop.
__global__ __launch_bounds__(256) void proj_t(
    const void* __restrict__ X0, const void* __restrict__ X1, const void* __restrict__ X2,
    const void* __restrict__ bq, const void* __restrict__ bk, const void* __restrict__ bv,
    const void* __restrict__ Wq, const void* __restrict__ Wk, const void* __restrict__ Wv,
    float* __restrict__ qo, float* __restrict__ ko, float* __restrict__ vo) {
    int p = blockIdx.y;
    const void* X    = (p == 0) ? X0 : (p == 1) ? X1 : X2;
    const void* W    = (p == 0) ? Wq : (p == 1) ? Wk : Wv;
    const void* bias = (p == 0) ? bq : (p == 1) ? bk : bv;
    float* out       = (p == 0) ? qo : (p == 1) ? ko : vo;

    __shared__ bool fxb, fwb, fbb;
    __shared__ __align__(16) float Xt[64 * 68];
    __shared__ __align__(16) float Ws[64 * 68];
    if (threadIdx.x == 0) {
        fxb = detect_bf16(X, 256);
        fwb = detect_bf16(W, 256);
        fbb = detect_bf16(bias, 64);
    }
    __syncthreads();
    const bool xb = fxb, wb = fwb, bb = fbb;

    const int t = threadIdx.x;
    const long row0 = (long)blockIdx.x * 64;
    const int row4 = (t >> 4) * 4;   // compute: 4 output rows
    const int col4 = (t & 15) * 4;   // compute: 4 output cols
    const int sr0 = (t >> 4) * 4;    // X stage: 4 source rows
    const int sk4 = (t & 15) * 4;    // X stage: 4 k within step
    const int wk  = t >> 2;          // W stage: k row 0..63
    const int wc0 = (t & 3) * 16;    // W stage: 16 cols

    // prefetch registers (branch is block-uniform; only one set is live)
    ushort4 xu0, xu1, xu2, xu3;
    float4  xf0, xf1, xf2, xf3;
    ushort8v wu0, wu1;
    float4  wf0, wf1, wf2, wf3;

    auto loadTile = [&](int k0) {
        if (xb) {
            const unsigned short* xp =
                (const unsigned short*)X + (row0 + sr0) * 1024 + k0 + sk4;
            xu0 = *(const ushort4*)(xp);
            xu1 = *(const ushort4*)(xp + 1024);
            xu2 = *(const ushort4*)(xp + 2048);
            xu3 = *(const ushort4*)(xp + 3072);
        } else {
            const float* xp = (const float*)X + (row0 + sr0) * 1024 + k0 + sk4;
            xf0 = *(const float4*)(xp);
            xf1 = *(const float4*)(xp + 1024);
            xf2 = *(const float4*)(xp + 2048);
            xf3 = *(const float4*)(xp + 3072);
        }
        if (wb) {
            const unsigned short* wp =
                (const unsigned short*)W + (long)(k0 + wk) * 64 + wc0;
            wu0 = *(const ushort8v*)(wp);
            wu1 = *(const ushort8v*)(wp + 8);
        } else {
            const float* wp = (const float*)W + (long)(k0 + wk) * 64 + wc0;
            wf0 = *(const float4*)(wp + 0);
            wf1 = *(const float4*)(wp + 4);
            wf2 = *(const float4*)(wp + 8);
            wf3 = *(const float4*)(wp + 12);
        }
    };
    auto writeTile = [&]() {
        if (xb) {
            *(float4*)&Xt[(sk4 + 0) * 68 + sr0] =
                make_float4(bf2f(xu0.x), bf2f(xu1.x), bf2f(xu2.x), bf2f(xu3.x));
            *(float4*)&Xt[(sk4 + 1) * 68 + sr0] =
                make_float4(bf2f(xu0.y), bf2f(xu1.y), bf2f(xu2.y), bf2f(xu3.y));
            *(float4*)&Xt[(sk4 + 2) * 68 + sr0] =
                make_float4(bf2f(xu0.z), bf2f(xu1.z), bf2f(xu2.z), bf2f(xu3.z));
            *(float4*)&Xt[(sk4 + 3) * 68 + sr0] =
                make_float4(bf2f(xu0.w), bf2f(xu1.w), bf2f(xu2.w), bf2f(xu3.w));
        } else {
            *(float4*)&Xt[(sk4 + 0) * 68 + sr0] = make_float4(xf0.x, xf1.x, xf2.x, xf3.x);
            *(float4*)&Xt[(sk4 + 1) * 68 + sr0] = make_float4(xf0.y, xf1.y, xf2.y, xf3.y);
            *(float4*)&Xt[(sk4 + 2) * 68 + sr0] = make_float4(xf0.z, xf1.z, xf2.z, xf3.z);
            *(float4*)&Xt[(sk4 + 3) * 68 + sr0] = make_float4(xf0.w, xf1.w, xf2.w, xf3.w);
        }
        float* wd = &Ws[wk * 68 + wc0];
        if (wb) {
            *(float4*)(wd + 0)  = make_float4(bf2f(wu0[0]), bf2f(wu0[1]), bf2f(wu0[2]), bf2f(wu0[3]));
            *(float4*)(wd + 4)  = make_float4(bf2f(wu0[4]), bf2f(wu0[5]), bf2f(wu0[6]), bf2f(wu0[7]));
            *(float4*)(wd + 8)  = make_float4(bf2f(wu1[0]), bf2f(wu1[1]), bf2f(wu1[2]), bf2f(wu1[3]));
            *(float4*)(wd + 12) = make_float4(bf2f(wu1[4]), bf2f(wu1[5]), bf2f(wu1[6]), bf2f(wu1[7]));
        } else {
            *(float4*)(wd + 0)  = wf0;
            *(float4*)(wd + 4)  = wf1;
            *(float4*)(wd + 8)  = wf2;
            *(float4*)(wd + 12) = wf3;
        }
    };

    loadTile(0);
    writeTile();
    __syncthreads();

    float acc[4][4] = {};
    for (int k0 = 0; k0 < 1024; k0 += 64) {
        const bool more = (k0 + 64 < 1024);
        if (more) loadTile(k0 + 64);     // issue next-tile loads (vmcnt waits at writeTile)
#pragma unroll 4
        for (int kk = 0; kk < 64; ++kk) {
            float4 xv = *(const float4*)&Xt[kk * 68 + row4];
            float4 wv = *(const float4*)&Ws[kk * 68 + col4];
            float xa[4] = {xv.x, xv.y, xv.z, xv.w};
            float wa[4] = {wv.x, wv.y, wv.z, wv.w};
#pragma unroll
            for (int i = 0; i < 4; ++i)
#pragma unroll
                for (int j = 0; j < 4; ++j) acc[i][j] += xa[i] * wa[j];
        }
        if (more) {
            __syncthreads();   // all reads of current tile done
            writeTile();
            __syncthreads();   // next tile visible
        }
    }

    float b0 = load_in(bias, col4 + 0, bb);
    float b1 = load_in(bias, col4 + 1, bb);
    float b2 = load_in(bias, col4 + 2, bb);
    float b3 = load_in(bias, col4 + 3, bb);
#pragma unroll
    for (int i = 0; i < 4; ++i)
        *(float4*)&out[(row0 + row4 + i) * 64 + col4] =
            make_float4(acc[i][0] + b0, acc[i][1] + b1, acc[i][2] + b2, acc[i][3] + b3);
}

// ---------------- attention: split flash kernel ----------------
// grid (64 q-tiles, 8 batches, ns splits) x 256. Block = 32 q-rows, keys [split*2048/ns ..).
// LDS: Qt[64][36] (d-major, pre-scaled), Kt[64][68], Pt[64][36] = 35 KB -> 4 blocks/CU.
// Thread: 2q x 4k (QK) / 2q x 4d (PV) register tile; K-tile register prefetch.
// ns>1: writes unnormalized o + per-row (m,l) partials; attn_merge combines.
__global__ __launch_bounds__(256) void attn_p(const float* __restrict__ q,
                                              const float* __restrict__ k,
                                              const float* __restrict__ v,
                                              float* __restrict__ ctx,
                                              float* __restrict__ po,
                                              float* __restrict__ pm,
                                              float* __restrict__ pl,
                                              int ns) {
    const int b = blockIdx.y;
    const int qt = blockIdx.x;       // 0..63
    const int split = blockIdx.z;    // 0..ns-1
    const int keys = 2048 / ns;
    const int NT = keys >> 6;
    const long kvbase = (long)b * 2048;
    const long qbase  = kvbase + (long)qt * 32;
    const long kstart = kvbase + (long)split * keys;

    __shared__ __align__(16) float Qt[64 * 36];
    __shared__ __align__(16) float Kt[64 * 68];
    __shared__ __align__(16) float Pt[64 * 36];

    const int tid = threadIdx.x;
    const int g16 = tid & 15;
    const int qg2 = (tid >> 4) * 2;   // 2 q-rows: qg2, qg2+1
    const int kg4 = g16 * 4;          // 4 keys
    const int dg4 = g16 * 4;          // 4 dims
    const int skr = (tid >> 4) * 4;   // K stage: 4 rows
    const int skd = g16 * 4;          // K stage: 4 dims

    // stage Q transposed (32 rows x 64 dims), pre-scaled by 1/sqrt(64)
    if (tid < 128) {
        const int sqr = (tid >> 4) * 4;   // 0..28
        const int sqd = (tid & 15) * 4;
        const float* qp = &q[(qbase + sqr) * 64 + sqd];
        float4 a0 = *(const float4*)(qp);
        float4 a1 = *(const float4*)(qp + 64);
        float4 a2 = *(const float4*)(qp + 128);
        float4 a3 = *(const float4*)(qp + 192);
        const float sc = 0.125f;
        *(float4*)&Qt[(sqd + 0) * 36 + sqr] = make_float4(a0.x * sc, a1.x * sc, a2.x * sc, a3.x * sc);
        *(float4*)&Qt[(sqd + 1) * 36 + sqr] = make_float4(a0.y * sc, a1.y * sc, a2.y * sc, a3.y * sc);
        *(float4*)&Qt[(sqd + 2) * 36 + sqr] = make_float4(a0.z * sc, a1.z * sc, a2.z * sc, a3.z * sc);
        *(float4*)&Qt[(sqd + 3) * 36 + sqr] = make_float4(a0.w * sc, a1.w * sc, a2.w * sc, a3.w * sc);
    }

    float4 ka0, ka1, ka2, ka3;
    auto loadK = [&](int t1) {
        const float* kp = &k[(kstart + t1 * 64 + skr) * 64 + skd];
        ka0 = *(const float4*)(kp);
        ka1 = *(const float4*)(kp + 64);
        ka2 = *(const float4*)(kp + 128);
        ka3 = *(const float4*)(kp + 192);
    };
    auto writeK = [&]() {
        *(float4*)&Kt[(skd + 0) * 68 + skr] = make_float4(ka0.x, ka1.x, ka2.x, ka3.x);
        *(float4*)&Kt[(skd + 1) * 68 + skr] = make_float4(ka0.y, ka1.y, ka2.y, ka3.y);
        *(float4*)&Kt[(skd + 2) * 68 + skr] = make_float4(ka0.z, ka1.z, ka2.z, ka3.z);
        *(float4*)&Kt[(skd + 3) * 68 + skr] = make_float4(ka0.w, ka1.w, ka2.w, ka3.w);
    };

    loadK(0);
    writeK();
    __syncthreads();

    float o[2][4] = {};
    float m[2] = {-INFINITY, -INFINITY};
    float l[2] = {};

    for (int t1 = 0; t1 < NT; ++t1) {
        if (t1 + 1 < NT) loadK(t1 + 1);   // issue prefetch; vmcnt wait is at writeK below

        // QK^T: s[2 q][4 k]
        float s[2][4] = {};
#pragma unroll 4
        for (int d = 0; d < 64; ++d) {
            float2 qv = *(const float2*)&Qt[d * 36 + qg2];
            float4 kv = *(const float4*)&Kt[d * 68 + kg4];
            float ka[4] = {kv.x, kv.y, kv.z, kv.w};
#pragma unroll
            for (int kj = 0; kj < 4; ++kj) {
                s[0][kj] += qv.x * ka[kj];
                s[1][kj] += qv.y * ka[kj];
            }
        }

        // online softmax update (16-lane k-groups)
#pragma unroll
        for (int qi = 0; qi < 2; ++qi) {
            float pmx = fmaxf(fmaxf(s[qi][0], s[qi][1]), fmaxf(s[qi][2], s[qi][3]));
            pmx = fmaxf(pmx, __shfl_xor(pmx, 1));
            pmx = fmaxf(pmx, __shfl_xor(pmx, 2));
            pmx = fmaxf(pmx, __shfl_xor(pmx, 4));
            pmx = fmaxf(pmx, __shfl_xor(pmx, 8));
            float mn = fmaxf(m[qi], pmx);
            float f = __expf(m[qi] - mn);
            m[qi] = mn;
            float ts = 0.f;
#pragma unroll
            for (int kj = 0; kj < 4; ++kj) {
                float pv = __expf(s[qi][kj] - mn);
                s[qi][kj] = pv;
                ts += pv;
            }
            ts += __shfl_xor(ts, 1);
            ts += __shfl_xor(ts, 2);
            ts += __shfl_xor(ts, 4);
            ts += __shfl_xor(ts, 8);
            l[qi] = l[qi] * f + ts;
#pragma unroll
            for (int di = 0; di < 4; ++di) o[qi][di] *= f;
        }

        // P^T to LDS (q<->d remap)
#pragma unroll
        for (int kj = 0; kj < 4; ++kj)
            *(float2*)&Pt[(kg4 + kj) * 36 + qg2] = make_float2(s[0][kj], s[1][kj]);
        __syncthreads();   // Pt ready; all Kt reads of this tile done

        // PV from Pt + V straight from L2
        const float* vb = &v[(kstart + t1 * 64) * 64 + dg4];
#pragma unroll 4
        for (int kk = 0; kk < 64; ++kk) {
            float2 p2 = *(const float2*)&Pt[kk * 36 + qg2];
            float4 v4 = *(const float4*)&vb[kk * 64];
            float va[4] = {v4.x, v4.y, v4.z, v4.w};
#pragma unroll
            for (int di = 0; di < 4; ++di) {
                o[0][di] += p2.x * va[di];
                o[1][di] += p2.y * va[di];
            }
        }

        if (t1 + 1 < NT) writeK();   // stage next K tile (prefetched regs)
        __syncthreads();             // Kt ready; Pt reads done
    }

    if (ns == 1) {
#pragma unroll
        for (int qi = 0; qi < 2; ++qi) {
            float inv = 1.f / l[qi];
            *(float4*)&ctx[(qbase + qg2 + qi) * 64 + dg4] =
                make_float4(o[qi][0] * inv, o[qi][1] * inv, o[qi][2] * inv, o[qi][3] * inv);
        }
    } else {
        const long idx = (long)(b * 64 + qt) * ns + split;
#pragma unroll
        for (int qi = 0; qi < 2; ++qi)
            *(float4*)&po[idx * 2048 + (qg2 + qi) * 64 + dg4] =
                make_float4(o[qi][0], o[qi][1], o[qi][2], o[qi][3]);
        if (g16 == 0) {
#pragma unroll
            for (int qi = 0; qi < 2; ++qi) {
                pm[idx * 32 + qg2 + qi] = m[qi];
                pl[idx * 32 + qg2 + qi] = l[qi];
            }
        }
    }
}

// ---------------- merge of split-softmax partials ----------------
// grid (4096) x 256: 4 rows x 64 dims per block. ctx = sum_s exp(m_s-M) o_s / sum_s exp(m_s-M) l_s
__global__ __launch_bounds__(256) void attn_merge(const float* __restrict__ po,
                                                  const float* __restrict__ pm,
                                                  const float* __restrict__ pl,
                                                  float* __restrict__ ctx,
                                                  int ns) {
    const int t = threadIdx.x;
    const long r = (long)blockIdx.x * 4 + (t >> 6);
    const int d = t & 63;
    const int b = (int)(r >> 11);
    const int rr = (int)(r & 2047);
    const int qt = rr >> 5;
    const int rloc = rr & 31;
    const long base = (long)(b * 64 + qt) * ns;
    float M = -INFINITY;
    for (int s = 0; s < ns; ++s) M = fmaxf(M, pm[(base + s) * 32 + rloc]);
    float L = 0.f, num = 0.f;
    for (int s = 0; s < ns; ++s) {
        float e = __expf(pm[(base + s) * 32 + rloc] - M);
        L += pl[(base + s) * 32 + rloc] * e;
        num += po[(base + s) * 2048 + rloc * 64 + d] * e;
    }
    ctx[r * 64 + d] = num / L;
}

// ---------------- output: out[16384][1024] = ctx @ Wo_sum + bo ----------------
__global__ __launch_bounds__(256) void out_t(const float* __restrict__ ctx,
                                             const float* __restrict__ wosum,
                                             const void* __restrict__ bo,
                                             float* __restrict__ out) {
    __shared__ __align__(16) float cr[8 * 64];
    __shared__ bool fbb;
    int t = threadIdx.x;
    long row0 = (long)blockIdx.x * 8;
    if (t == 0) fbb = detect_bf16(bo, 256);
    if (t < 128) {
        int r = t >> 4, d4 = (t & 15) * 4;
        *(float4*)&cr[r * 64 + d4] = *(const float4*)&ctx[(row0 + r) * 64 + d4];
    }
    __syncthreads();
    bool bob = fbb;
    int c = t * 4;
    float a[8][4];
    {
        float b0 = load_in(bo, c + 0, bob), b1 = load_in(bo, c + 1, bob);
        float b2 = load_in(bo, c + 2, bob), b3 = load_in(bo, c + 3, bob);
#pragma unroll
        for (int r = 0; r < 8; ++r) { a[r][0] = b0; a[r][1] = b1; a[r][2] = b2; a[r][3] = b3; }
    }
#pragma unroll 4
    for (int d = 0; d < 64; ++d) {
        float4 w4 = *(const float4*)&wosum[d * 1024 + c];
#pragma unroll
        for (int r = 0; r < 8; ++r) {
            float cv = cr[r * 64 + d];
            a[r][0] += cv * w4.x;
            a[r][1] += cv * w4.y;
            a[r][2] += cv * w4.z;
            a[r][3] += cv * w4.w;
        }
    }
#pragma unroll
    for (int r = 0; r < 8; ++r)
        *(float4*)&out[(row0 + r) * 1024 + c] = make_float4(a[r][0], a[r][1], a[r][2], a[r][3]);
}

extern "C" void kernel_launch(void* const* d_in, const int* in_sizes, int n_in,
                              void* d_out, int out_size, void* d_ws, size_t ws_size,
                              hipStream_t stream) {
    // Defensive routing by size class (identity if inputs are in dict order):
    // 16777216 -> query,key,value ; 65536 -> Wq,Wk,Wv ; 64 -> bq,bk,bv ;
    // 1048576 -> Wo ; 1024 -> bo. in_sizes are element counts (dtype-independent).
    const void* big[3] = {0, 0, 0};  int nbig = 0;
    const void* w64k[3] = {0, 0, 0}; int nw = 0;
    const void* b64[3] = {0, 0, 0};  int nb = 0;
    const void* Wo = 0; const void* bo = 0;
    for (int i = 0; i < n_in; ++i) {
        int s = in_sizes[i];
        if (s == 16777216 && nbig < 3)     big[nbig++] = d_in[i];
        else if (s == 65536 && nw < 3)     w64k[nw++] = d_in[i];
        else if (s == 64 && nb < 3)        b64[nb++] = d_in[i];
        else if (s == 1048576)             Wo = d_in[i];
        else if (s == 1024)                bo = d_in[i];
    }
    const void* query = big[0]  ? big[0]  : d_in[0];
    const void* key   = big[1]  ? big[1]  : d_in[1];
    const void* value = big[2]  ? big[2]  : d_in[2];
    const void* Wq    = w64k[0] ? w64k[0] : d_in[3];
    const void* Wk    = w64k[1] ? w64k[1] : d_in[5];
    const void* Wv    = w64k[2] ? w64k[2] : d_in[7];
    const void* bq    = b64[0]  ? b64[0]  : d_in[4];
    const void* bk    = b64[1]  ? b64[1]  : d_in[6];
    const void* bv    = b64[2]  ? b64[2]  : d_in[8];
    if (!Wo) Wo = d_in[9];
    if (!bo) bo = d_in[10];
    float* out = (float*)d_out;

    char* ws = (char*)d_ws;
    float* wosum = (float*)(ws);                      // 256 KB (1 MB reserved)
    float* q     = (float*)(ws + 1048576);            // 4 MB
    float* k     = (float*)(ws + 1048576 + 4194304);  // 4 MB
    float* v     = (float*)(ws + 1048576 + 2*4194304);// 4 MB
    float* ctx   = (float*)(ws + 1048576 + 3*4194304);// 4 MB
    // split-softmax partials (ns=2): po 8 MB, pm/pl 128 KB each
    const size_t PO_OFF = 1048576 + (size_t)4 * 4194304;   // 17825792
    int ns = (ws_size >= PO_OFF + 2 * 4194304ull + 2 * 131072ull) ? 2 : 1;
    float* po = (float*)(ws + PO_OFF);
    float* pm = (float*)(ws + PO_OFF + (size_t)ns * 4194304);
    float* pl = pm + (size_t)ns * 16384;

    hipLaunchKernelGGL(prep_wosum, dim3(256),        dim3(256), 0, stream, Wo, wosum);
    hipLaunchKernelGGL(proj_t,     dim3(256, 3),     dim3(256), 0, stream,
                       query, key, value, bq, bk, bv, Wq, Wk, Wv, q, k, v);
    hipLaunchKernelGGL(attn_p,     dim3(64, 8, ns),  dim3(256), 0, stream,
                       q, k, v, ctx, po, pm, pl, ns);
    if (ns > 1)
        hipLaunchKernelGGL(attn_merge, dim3(4096),   dim3(256), 0, stream, po, pm, pl, ctx, ns);
    hipLaunchKernelGGL(out_t,      dim3(2048),       dim3(256), 0, stream, ctx, wosum, bo, out);
}

// Round 4
// 543.785 us; speedup vs baseline: 6.1408x; 1.0008x over previous
//
#include <hip/hip_runtime.h>

// B=8, S=2048, D_MODEL=1024, HEAD_DIM=64, NUM_HEADS=16 (all heads identical).
// out = softmax((X Wq)(X Wk)^T / 8) (X Wv) @ Wo_sum + bo, Wo_sum[d,j] = sum_h Wo[h*64+d, j].
// Round 8: LDS bank-conflict fix (all staging writes had the fast lane index on a x4-stride
// coefficient -> 4-8 way conflicts, SQ_LDS_BANK_CONFLICT=1.38e7). Rule applied everywhere:
// fast lane index (tid&15) multiplies the unit-stride LDS dim. attn back to 64-row tiles
// with 4x4 register tile (16 FMA / 2 b128) + ns=4 key splits for grid 1024. P stored
// q-major so PV reads are broadcasts. proj_t: X kept row-major (no transpose needed; compute
// reads are 16-lane broadcasts), same conflict-free staging, double-buffered. out_t: 16 rows.

typedef __attribute__((ext_vector_type(8))) unsigned short ushort8v;

__device__ __forceinline__ float bf2f(unsigned short u) {
    unsigned int x = ((unsigned int)u) << 16;
    return __builtin_bit_cast(float, x);
}

__device__ __forceinline__ bool detect_bf16(const void* p, int nwords) {
    const unsigned short* w = (const unsigned short*)p;
    int sane = 0;
    for (int i = 0; i < nwords; ++i) {
        unsigned e = (w[i] >> 7) & 0xFF;
        sane += (e == 0 || (e >= 0x60 && e <= 0x9F)) ? 1 : 0;
    }
    return sane * 10 >= nwords * 9;
}

__device__ __forceinline__ float load_in(const void* p, long idx, bool isbf16) {
    return isbf16 ? bf2f(((const unsigned short*)p)[idx]) : ((const float*)p)[idx];
}

// ---------------- Wo_sum[64][1024] (f32), vectorized ----------------
// grid 64 x 256; thread handles 4 consecutive n.
__global__ __launch_bounds__(256) void prep_wosum(const void* __restrict__ Wo,
                                                  float* __restrict__ wosum) {
    __shared__ bool fwb;
    if (threadIdx.x == 0) fwb = detect_bf16(Wo, 256);
    __syncthreads();
    bool wb = fwb;
    int base = (blockIdx.x * 256 + threadIdx.x) * 4;   // 0..65532
    int d = base >> 10, n = base & 1023;
    float4 s = make_float4(0.f, 0.f, 0.f, 0.f);
#pragma unroll
    for (int h = 0; h < 16; ++h) {
        long off = (long)(h * 64 + d) * 1024 + n;
        if (wb) {
            ushort4 u = *(const ushort4*)((const unsigned short*)Wo + off);
            s.x += bf2f(u.x); s.y += bf2f(u.y); s.z += bf2f(u.z); s.w += bf2f(u.w);
        } else {
            float4 f = *(const float4*)((const float*)Wo + off);
            s.x += f.x; s.y += f.y; s.z += f.z; s.w += f.w;
        }
    }
    *(float4*)&wosum[base] = s;
}

// ---------------- projections: q/k/v[16384][64] f32 = X[16384][1024] @ W[1024][64] + b ----
// grid (256, 3) x 256. 64x64 output tile, K-step 64, 4x4 register tile, double-buffered.
// LDS: Xs[64 rows][68 k] (row-major, NO transpose), Ws[64 k][68 col]. Staging: lanes
// tid>>4 pick the strided dim (rows of Xs / k of Ws), tid&15 sweep unit-stride -> conflict-
// free. Compute: X reads are 16-lane broadcasts; Ws reads 16-addr b128 (2-way, free).
__global__ __launch_bounds__(256) void proj_t(
    const void* __restrict__ X0, const void* __restrict__ X1, const void* __restrict__ X2,
    const void* __restrict__ bq, const void* __restrict__ bk, const void* __restrict__ bv,
    const void* __restrict__ Wq, const void* __restrict__ Wk, const void* __restrict__ Wv,
    float* __restrict__ qo, float* __restrict__ ko, float* __restrict__ vo) {
    int p = blockIdx.y;
    const void* X    = (p == 0) ? X0 : (p == 1) ? X1 : X2;
    const void* W    = (p == 0) ? Wq : (p == 1) ? Wk : Wv;
    const void* bias = (p == 0) ? bq : (p == 1) ? bk : bv;
    float* out       = (p == 0) ? qo : (p == 1) ? ko : vo;

    __shared__ bool fxb, fwb, fbb;
    __shared__ __align__(16) float Xs[64 * 68];
    __shared__ __align__(16) float Ws[64 * 68];
    if (threadIdx.x == 0) {
        fxb = detect_bf16(X, 256);
        fwb = detect_bf16(W, 256);
        fbb = detect_bf16(bias, 64);
    }
    __syncthreads();
    const bool xb = fxb, wb = fwb, bb = fbb;

    const int t = threadIdx.x;
    const int g16 = t & 15;
    const int w4 = t >> 4;          // 0..15
    const long row0 = (long)blockIdx.x * 64;
    const int row4 = 4 * w4;        // compute: 4 output rows
    const int col4 = 4 * g16;       // compute: 4 output cols
    const int sR = 4 * w4;          // staging: strided-dim base (Xs row / Ws k)
    const int sC = 4 * g16;         // staging: unit-stride base

    ushort4 xu0, xu1, xu2, xu3, wu0, wu1, wu2, wu3;
    float4  xf0, xf1, xf2, xf3, wf0, wf1, wf2, wf3;

    auto loadTile = [&](int k0) {
        if (xb) {
            const unsigned short* xp =
                (const unsigned short*)X + (row0 + sR) * 1024 + k0 + sC;
            xu0 = *(const ushort4*)(xp);
            xu1 = *(const ushort4*)(xp + 1024);
            xu2 = *(const ushort4*)(xp + 2048);
            xu3 = *(const ushort4*)(xp + 3072);
        } else {
            const float* xp = (const float*)X + (row0 + sR) * 1024 + k0 + sC;
            xf0 = *(const float4*)(xp);
            xf1 = *(const float4*)(xp + 1024);
            xf2 = *(const float4*)(xp + 2048);
            xf3 = *(const float4*)(xp + 3072);
        }
        if (wb) {
            const unsigned short* wp =
                (const unsigned short*)W + (long)(k0 + sR) * 64 + sC;
            wu0 = *(const ushort4*)(wp);
            wu1 = *(const ushort4*)(wp + 64);
            wu2 = *(const ushort4*)(wp + 128);
            wu3 = *(const ushort4*)(wp + 192);
        } else {
            const float* wp = (const float*)W + (long)(k0 + sR) * 64 + sC;
            wf0 = *(const float4*)(wp);
            wf1 = *(const float4*)(wp + 64);
            wf2 = *(const float4*)(wp + 128);
            wf3 = *(const float4*)(wp + 192);
        }
    };
    auto writeTile = [&]() {
        if (xb) {
            *(float4*)&Xs[(sR + 0) * 68 + sC] = make_float4(bf2f(xu0.x), bf2f(xu0.y), bf2f(xu0.z), bf2f(xu0.w));
            *(float4*)&Xs[(sR + 1) * 68 + sC] = make_float4(bf2f(xu1.x), bf2f(xu1.y), bf2f(xu1.z), bf2f(xu1.w));
            *(float4*)&Xs[(sR + 2) * 68 + sC] = make_float4(bf2f(xu2.x), bf2f(xu2.y), bf2f(xu2.z), bf2f(xu2.w));
            *(float4*)&Xs[(sR + 3) * 68 + sC] = make_float4(bf2f(xu3.x), bf2f(xu3.y), bf2f(xu3.z), bf2f(xu3.w));
        } else {
            *(float4*)&Xs[(sR + 0) * 68 + sC] = xf0;
            *(float4*)&Xs[(sR + 1) * 68 + sC] = xf1;
            *(float4*)&Xs[(sR + 2) * 68 + sC] = xf2;
            *(float4*)&Xs[(sR + 3) * 68 + sC] = xf3;
        }
        if (wb) {
            *(float4*)&Ws[(sR + 0) * 68 + sC] = make_float4(bf2f(wu0.x), bf2f(wu0.y), bf2f(wu0.z), bf2f(wu0.w));
            *(float4*)&Ws[(sR + 1) * 68 + sC] = make_float4(bf2f(wu1.x), bf2f(wu1.y), bf2f(wu1.z), bf2f(wu1.w));
            *(float4*)&Ws[(sR + 2) * 68 + sC] = make_float4(bf2f(wu2.x), bf2f(wu2.y), bf2f(wu2.z), bf2f(wu2.w));
            *(float4*)&Ws[(sR + 3) * 68 + sC] = make_float4(bf2f(wu3.x), bf2f(wu3.y), bf2f(wu3.z), bf2f(wu3.w));
        } else {
            *(float4*)&Ws[(sR + 0) * 68 + sC] = wf0;
            *(float4*)&Ws[(sR + 1) * 68 + sC] = wf1;
            *(float4*)&Ws[(sR + 2) * 68 + sC] = wf2;
            *(float4*)&Ws[(sR + 3) * 68 + sC] = wf3;
        }
    };

    loadTile(0);
    writeTile();
    __syncthreads();

    float acc[4][4] = {};
    for (int k0 = 0; k0 < 1024; k0 += 64) {
        const bool more = (k0 + 64 < 1024);
        if (more) loadTile(k0 + 64);
#pragma unroll 2
        for (int kk = 0; kk < 64; kk += 4) {
            float4 xq[4], wv[4];
#pragma unroll
            for (int qi = 0; qi < 4; ++qi) xq[qi] = *(const float4*)&Xs[(row4 + qi) * 68 + kk];
#pragma unroll
            for (int j = 0; j < 4; ++j) wv[j] = *(const float4*)&Ws[(kk + j) * 68 + col4];
#pragma unroll
            for (int qi = 0; qi < 4; ++qi) {
                float xa[4] = {xq[qi].x, xq[qi].y, xq[qi].z, xq[qi].w};
#pragma unroll
                for (int j = 0; j < 4; ++j) {
                    acc[qi][0] += xa[j] * wv[j].x;
                    acc[qi][1] += xa[j] * wv[j].y;
                    acc[qi][2] += xa[j] * wv[j].z;
                    acc[qi][3] += xa[j] * wv[j].w;
                }
            }
        }
        if (more) {
            __syncthreads();
            writeTile();
            __syncthreads();
        }
    }

    float b0 = load_in(bias, col4 + 0, bb);
    float b1 = load_in(bias, col4 + 1, bb);
    float b2 = load_in(bias, col4 + 2, bb);
    float b3 = load_in(bias, col4 + 3, bb);
#pragma unroll
    for (int qi = 0; qi < 4; ++qi)
        *(float4*)&out[(row0 + row4 + qi) * 64 + col4] =
            make_float4(acc[qi][0] + b0, acc[qi][1] + b1, acc[qi][2] + b2, acc[qi][3] + b3);
}

// ---------------- attention: split flash kernel, 64-row tiles, 4x4 register tile ----------
// grid (32 q-tiles, 8 batches, ns) x 256. Keys per split = 2048/ns; K-tile = 64.
// LDS: Qt[64 d][68 q] (pre-scaled), Kt[64 d][68 k], Pt[64 q][72 k] = 52 KB -> 3 blocks/CU.
// Staging: lanes tid&15 sweep rows (unit stride of Qt/Kt), tid>>4 pick dims -> conflict-free.
// Pt is q-major: writes sweep k with fast lanes (conflict-free), PV reads are broadcasts.
__global__ __launch_bounds__(256) void attn_p(const float* __restrict__ q,
                                              const float* __restrict__ k,
                                              const float* __restrict__ v,
                                              float* __restrict__ ctx,
                                              float* __restrict__ po,
                                              float* __restrict__ pm,
                                              float* __restrict__ pl,
                                              int ns) {
    const int b = blockIdx.y;
    const int qt = blockIdx.x;       // 0..31
    const int split = blockIdx.z;    // 0..ns-1
    const int keys = 2048 / ns;
    const int NT = keys >> 6;
    const long kvbase = (long)b * 2048;
    const long qbase  = kvbase + (long)qt * 64;
    const long kstart = kvbase + (long)split * keys;

    __shared__ __align__(16) float Qt[64 * 68];
    __shared__ __align__(16) float Kt[64 * 68];
    __shared__ __align__(16) float Pt[64 * 72];

    const int tid = threadIdx.x;
    const int g16 = tid & 15;
    const int w4 = tid >> 4;          // 0..15
    const int qg4 = 4 * w4;           // 4 q-rows
    const int kg4 = 4 * g16;          // 4 keys
    const int dg4 = 4 * g16;          // 4 dims
    const int sr = 4 * g16;           // staging: 4 rows (unit-stride dim)
    const int sd = 4 * w4;            // staging: 4 dims (strided dim)

    // stage Q (rows sr..sr+3, dims sd..sd+3), pre-scaled by 1/8
    {
        const float* qp = &q[(qbase + sr) * 64 + sd];
        float4 a0 = *(const float4*)(qp);
        float4 a1 = *(const float4*)(qp + 64);
        float4 a2 = *(const float4*)(qp + 128);
        float4 a3 = *(const float4*)(qp + 192);
        const float sc = 0.125f;
        *(float4*)&Qt[(sd + 0) * 68 + sr] = make_float4(a0.x * sc, a1.x * sc, a2.x * sc, a3.x * sc);
        *(float4*)&Qt[(sd + 1) * 68 + sr] = make_float4(a0.y * sc, a1.y * sc, a2.y * sc, a3.y * sc);
        *(float4*)&Qt[(sd + 2) * 68 + sr] = make_float4(a0.z * sc, a1.z * sc, a2.z * sc, a3.z * sc);
        *(float4*)&Qt[(sd + 3) * 68 + sr] = make_float4(a0.w * sc, a1.w * sc, a2.w * sc, a3.w * sc);
    }

    float4 ka0, ka1, ka2, ka3;
    auto loadK = [&](int t1) {
        const float* kp = &k[(kstart + t1 * 64 + sr) * 64 + sd];
        ka0 = *(const float4*)(kp);
        ka1 = *(const float4*)(kp + 64);
        ka2 = *(const float4*)(kp + 128);
        ka3 = *(const float4*)(kp + 192);
    };
    auto writeK = [&]() {
        *(float4*)&Kt[(sd + 0) * 68 + sr] = make_float4(ka0.x, ka1.x, ka2.x, ka3.x);
        *(float4*)&Kt[(sd + 1) * 68 + sr] = make_float4(ka0.y, ka1.y, ka2.y, ka3.y);
        *(float4*)&Kt[(sd + 2) * 68 + sr] = make_float4(ka0.z, ka1.z, ka2.z, ka3.z);
        *(float4*)&Kt[(sd + 3) * 68 + sr] = make_float4(ka0.w, ka1.w, ka2.w, ka3.w);
    };

    loadK(0);
    writeK();
    __syncthreads();

    float o[4][4] = {};
    float m[4] = {-INFINITY, -INFINITY, -INFINITY, -INFINITY};
    float l[4] = {};

    for (int t1 = 0; t1 < NT; ++t1) {
        if (t1 + 1 < NT) loadK(t1 + 1);

        // QK^T: s[4 q][4 k]
        float s[4][4] = {};
#pragma unroll 4
        for (int d = 0; d < 64; ++d) {
            float4 qv = *(const float4*)&Qt[d * 68 + qg4];   // 16-lane broadcast
            float4 kv = *(const float4*)&Kt[d * 68 + kg4];   // 16-addr b128, 2-way
            float qa[4] = {qv.x, qv.y, qv.z, qv.w};
            float ka[4] = {kv.x, kv.y, kv.z, kv.w};
#pragma unroll
            for (int qi = 0; qi < 4; ++qi)
#pragma unroll
                for (int kj = 0; kj < 4; ++kj) s[qi][kj] += qa[qi] * ka[kj];
        }

        // online softmax (reduce over 16-lane k-groups)
#pragma unroll
        for (int qi = 0; qi < 4; ++qi) {
            float pmx = fmaxf(fmaxf(s[qi][0], s[qi][1]), fmaxf(s[qi][2], s[qi][3]));
            pmx = fmaxf(pmx, __shfl_xor(pmx, 1));
            pmx = fmaxf(pmx, __shfl_xor(pmx, 2));
            pmx = fmaxf(pmx, __shfl_xor(pmx, 4));
            pmx = fmaxf(pmx, __shfl_xor(pmx, 8));
            float mn = fmaxf(m[qi], pmx);
            float f = __expf(m[qi] - mn);
            m[qi] = mn;
            float ts = 0.f;
#pragma unroll
            for (int kj = 0; kj < 4; ++kj) {
                float pv = __expf(s[qi][kj] - mn);
                s[qi][kj] = pv;
                ts += pv;
            }
            ts += __shfl_xor(ts, 1);
            ts += __shfl_xor(ts, 2);
            ts += __shfl_xor(ts, 4);
            ts += __shfl_xor(ts, 8);
            l[qi] = l[qi] * f + ts;
#pragma unroll
            for (int di = 0; di < 4; ++di) o[qi][di] *= f;
        }

        // P to LDS, q-major (writes sweep k with fast lanes -> conflict-free)
#pragma unroll
        for (int qi = 0; qi < 4; ++qi)
            *(float4*)&Pt[(qg4 + qi) * 72 + kg4] =
                make_float4(s[qi][0], s[qi][1], s[qi][2], s[qi][3]);
        __syncthreads();   // Pt ready; all Kt reads done

        // PV: kk-step-4; P reads broadcast, V from L2 (coalesced 256B/16-lane group)
        const float* vb = &v[(kstart + t1 * 64) * 64 + dg4];
#pragma unroll 2
        for (int kk = 0; kk < 64; kk += 4) {
            float4 p4[4], v4[4];
#pragma unroll
            for (int qi = 0; qi < 4; ++qi) p4[qi] = *(const float4*)&Pt[(qg4 + qi) * 72 + kk];
#pragma unroll
            for (int j = 0; j < 4; ++j) v4[j] = *(const float4*)&vb[(kk + j) * 64];
#pragma unroll
            for (int qi = 0; qi < 4; ++qi) {
                float pa[4] = {p4[qi].x, p4[qi].y, p4[qi].z, p4[qi].w};
#pragma unroll
                for (int j = 0; j < 4; ++j) {
                    o[qi][0] += pa[j] * v4[j].x;
                    o[qi][1] += pa[j] * v4[j].y;
                    o[qi][2] += pa[j] * v4[j].z;
                    o[qi][3] += pa[j] * v4[j].w;
                }
            }
        }

        if (t1 + 1 < NT) writeK();
        __syncthreads();   // Kt ready; Pt reads done
    }

    if (ns == 1) {
#pragma unroll
        for (int qi = 0; qi < 4; ++qi) {
            float inv = 1.f / l[qi];
            *(float4*)&ctx[(qbase + qg4 + qi) * 64 + dg4] =
                make_float4(o[qi][0] * inv, o[qi][1] * inv, o[qi][2] * inv, o[qi][3] * inv);
        }
    } else {
        const long idx = (long)(b * 32 + qt) * ns + split;
#pragma unroll
        for (int qi = 0; qi < 4; ++qi)
            *(float4*)&po[idx * 4096 + (qg4 + qi) * 64 + dg4] =
                make_float4(o[qi][0], o[qi][1], o[qi][2], o[qi][3]);
        if (g16 == 0) {
#pragma unroll
            for (int qi = 0; qi < 4; ++qi) {
                pm[idx * 64 + qg4 + qi] = m[qi];
                pl[idx * 64 + qg4 + qi] = l[qi];
            }
        }
    }
}

// ---------------- merge of split-softmax partials ----------------
// grid (4096) x 256: 4 rows x 64 dims per block.
__global__ __launch_bounds__(256) void attn_merge(const float* __restrict__ po,
                                                  const float* __restrict__ pm,
                                                  const float* __restrict__ pl,
                                                  float* __restrict__ ctx,
                                                  int ns) {
    const int t = threadIdx.x;
    const long r = (long)blockIdx.x * 4 + (t >> 6);
    const int d = t & 63;
    const int b = (int)(r >> 11);
    const int rr = (int)(r & 2047);
    const int qt = rr >> 6;
    const int rloc = rr & 63;
    const long base = (long)(b * 32 + qt) * ns;
    float M = -INFINITY;
    for (int s = 0; s < ns; ++s) M = fmaxf(M, pm[(base + s) * 64 + rloc]);
    float L = 0.f, num = 0.f;
    for (int s = 0; s < ns; ++s) {
        float e = __expf(pm[(base + s) * 64 + rloc] - M);
        L += pl[(base + s) * 64 + rloc] * e;
        num += po[(base + s) * 4096 + rloc * 64 + d] * e;
    }
    ctx[r * 64 + d] = num / L;
}

// ---------------- output: out[16384][1024] = ctx @ Wo_sum + bo, 16 rows/block ----------------
__global__ __launch_bounds__(256) void out_t(const float* __restrict__ ctx,
                                             const float* __restrict__ wosum,
                                             const void* __restrict__ bo,
                                             float* __restrict__ out) {
    __shared__ __align__(16) float cr[16 * 64];
    __shared__ bool fbb;
    int t = threadIdx.x;
    long row0 = (long)blockIdx.x * 16;
    if (t == 0) fbb = detect_bf16(bo, 256);
    *(float4*)&cr[t * 4] = *(const float4*)&ctx[row0 * 64 + t * 4];
    __syncthreads();
    bool bob = fbb;
    int c = t * 4;
    float a[16][4];
    {
        float b0 = load_in(bo, c + 0, bob), b1 = load_in(bo, c + 1, bob);
        float b2 = load_in(bo, c + 2, bob), b3 = load_in(bo, c + 3, bob);
#pragma unroll
        for (int r = 0; r < 16; ++r) { a[r][0] = b0; a[r][1] = b1; a[r][2] = b2; a[r][3] = b3; }
    }
#pragma unroll 4
    for (int d = 0; d < 64; ++d) {
        float4 w4 = *(const float4*)&wosum[d * 1024 + c];
#pragma unroll
        for (int r = 0; r < 16; ++r) {
            float cv = cr[r * 64 + d];
            a[r][0] += cv * w4.x;
            a[r][1] += cv * w4.y;
            a[r][2] += cv * w4.z;
            a[r][3] += cv * w4.w;
        }
    }
#pragma unroll
    for (int r = 0; r < 16; ++r)
        *(float4*)&out[(row0 + r) * 1024 + c] = make_float4(a[r][0], a[r][1], a[r][2], a[r][3]);
}

extern "C" void kernel_launch(void* const* d_in, const int* in_sizes, int n_in,
                              void* d_out, int out_size, void* d_ws, size_t ws_size,
                              hipStream_t stream) {
    // Defensive routing by size class (identity if inputs are in dict order):
    const void* big[3] = {0, 0, 0};  int nbig = 0;
    const void* w64k[3] = {0, 0, 0}; int nw = 0;
    const void* b64[3] = {0, 0, 0};  int nb = 0;
    const void* Wo = 0; const void* bo = 0;
    for (int i = 0; i < n_in; ++i) {
        int s = in_sizes[i];
        if (s == 16777216 && nbig < 3)     big[nbig++] = d_in[i];
        else if (s == 65536 && nw < 3)     w64k[nw++] = d_in[i];
        else if (s == 64 && nb < 3)        b64[nb++] = d_in[i];
        else if (s == 1048576)             Wo = d_in[i];
        else if (s == 1024)                bo = d_in[i];
    }
    const void* query = big[0]  ? big[0]  : d_in[0];
    const void* key   = big[1]  ? big[1]  : d_in[1];
    const void* value = big[2]  ? big[2]  : d_in[2];
    const void* Wq    = w64k[0] ? w64k[0] : d_in[3];
    const void* Wk    = w64k[1] ? w64k[1] : d_in[5];
    const void* Wv    = w64k[2] ? w64k[2] : d_in[7];
    const void* bq    = b64[0]  ? b64[0]  : d_in[4];
    const void* bk    = b64[1]  ? b64[1]  : d_in[6];
    const void* bv    = b64[2]  ? b64[2]  : d_in[8];
    if (!Wo) Wo = d_in[9];
    if (!bo) bo = d_in[10];
    float* out = (float*)d_out;

    char* ws = (char*)d_ws;
    float* wosum = (float*)(ws);                      // 256 KB (1 MB reserved)
    float* q     = (float*)(ws + 1048576);            // 4 MB
    float* k     = (float*)(ws + 1048576 + 4194304);  // 4 MB
    float* v     = (float*)(ws + 1048576 + 2*4194304);// 4 MB
    float* ctx   = (float*)(ws + 1048576 + 3*4194304);// 4 MB
    const size_t PO_OFF = 1048576 + (size_t)4 * 4194304;   // 17825792
    // partials: po ns*4MB, pm/pl ns*64KB each
    int ns = 1;
    if (ws_size >= PO_OFF + 4 * 4194304ull + 2 * 4 * 65536ull)      ns = 4;
    else if (ws_size >= PO_OFF + 2 * 4194304ull + 2 * 2 * 65536ull) ns = 2;
    float* po = (float*)(ws + PO_OFF);
    float* pm = (float*)(ws + PO_OFF + (size_t)ns * 4194304);
    float* pl = pm + (size_t)ns * 16384;

    hipLaunchKernelGGL(prep_wosum, dim3(64),         dim3(256), 0, stream, Wo, wosum);
    hipLaunchKernelGGL(proj_t,     dim3(256, 3),     dim3(256), 0, stream,
                       query, key, value, bq, bk, bv, Wq, Wk, Wv, q, k, v);
    hipLaunchKernelGGL(attn_p,     dim3(32, 8, ns),  dim3(256), 0, stream,
                       q, k, v, ctx, po, pm, pl, ns);
    if (ns > 1)
        hipLaunchKernelGGL(attn_merge, dim3(4096),   dim3(256), 0, stream, po, pm, pl, ctx, ns);
    hipLaunchKernelGGL(out_t,      dim3(1024),       dim3(256), 0, stream, ctx, wosum, bo, out);
}